// Round 1
// baseline (116.886 us; speedup 1.0000x reference)
//
#include <hip/hip_runtime.h>

// Problem constants (fixed by the reference):
//   x: [B=16, C=D=64, H=64, W=64] fp32 NCHW; emb: [K=512, D=64] fp32
//   out = concat(one_hot [N=65536, 512] fp32, quantized [16,64,64,64] fp32)
constexpr int D  = 64;
constexpr int K  = 512;
constexpr int N  = 65536;     // B*H*W
constexpr int HW = 4096;      // H*W
constexpr int TPB = 256;
constexpr int PIX_PER_BLK = 64;
constexpr int WAVES = 4;
constexpr int CODES_PER_WAVE = K / WAVES;   // 128

__global__ __launch_bounds__(TPB, 4) void vq_kernel(
    const float* __restrict__ x, const float* __restrict__ emb,
    float* __restrict__ enc, float* __restrict__ quant)
{
    __shared__ float s_esq[K];                 // ||e_k||^2
    __shared__ float s_cs[2 * WAVES][PIX_PER_BLK];
    __shared__ int   s_ci[2 * WAVES][PIX_PER_BLK];
    __shared__ int   s_idx[PIX_PER_BLK];

    const int tid  = threadIdx.x;
    const int lane = tid & 63;
    // readfirstlane => SGPR => uniform: lets the compiler emit s_load for emb rows
    const int wave = __builtin_amdgcn_readfirstlane(tid >> 6);

    const int pixbase = blockIdx.x * PIX_PER_BLK;   // 64 consecutive (h,w) in one b
    const int b   = pixbase >> 12;                  // / 4096
    const int hw0 = pixbase & (HW - 1);

    // ---- block-cooperative e_sq (redundant per block; ~1.5% of FMA work) ----
    for (int k = tid; k < K; k += TPB) {
        const float4* er = (const float4*)(emb + k * D);
        float a0 = 0.f, a1 = 0.f, a2 = 0.f, a3 = 0.f;
        #pragma unroll
        for (int j = 0; j < D / 4; ++j) {
            float4 v = er[j];
            a0 = fmaf(v.x, v.x, a0);
            a1 = fmaf(v.y, v.y, a1);
            a2 = fmaf(v.z, v.z, a2);
            a3 = fmaf(v.w, v.w, a3);
        }
        s_esq[k] = (a0 + a1) + (a2 + a3);
    }

    // ---- this lane's pixel vector (NCHW gather: stride HW per channel, lanes coalesced) ----
    const float* xp = x + (size_t)b * D * HW + hw0 + lane;
    float xr[D];
    #pragma unroll
    for (int d = 0; d < D; ++d) xr[d] = xp[(size_t)d * HW];

    __syncthreads();

    // ---- scan this wave's 128-code chunk; track top-2 (score, index) ----
    const int kbase = wave * CODES_PER_WAVE;
    float bs = 3.4e38f, ss = 3.4e38f;
    int   bi = 0x7fffffff, si = 0x7fffffff;
    for (int k = kbase; k < kbase + CODES_PER_WAVE; ++k) {
        const float* ep = emb + k * D;     // k wave-uniform -> s_load
        float a0 = 0.f, a1 = 0.f, a2 = 0.f, a3 = 0.f;
        #pragma unroll
        for (int d = 0; d < D; d += 4) {
            a0 = fmaf(xr[d + 0], ep[d + 0], a0);
            a1 = fmaf(xr[d + 1], ep[d + 1], a1);
            a2 = fmaf(xr[d + 2], ep[d + 2], a2);
            a3 = fmaf(xr[d + 3], ep[d + 3], a3);
        }
        float dot = (a0 + a1) + (a2 + a3);
        float s = fmaf(-2.0f, dot, s_esq[k]);   // x_sq dropped (row-constant)
        if (s < bs)      { ss = bs; si = bi; bs = s; bi = k; }
        else if (s < ss) { ss = s;  si = k; }
    }
    s_cs[2 * wave + 0][lane] = bs;  s_ci[2 * wave + 0][lane] = bi;
    s_cs[2 * wave + 1][lane] = ss;  s_ci[2 * wave + 1][lane] = si;
    __syncthreads();

    // ---- combine across waves + fp64 refinement of near-ties (threads 0..63) ----
    if (tid < PIX_PER_BLK) {
        float fbs = 3.4e38f, fss = 3.4e38f;
        int   fbi = 0x7fffffff, fsi = 0x7fffffff;
        #pragma unroll
        for (int j = 0; j < 2 * WAVES; ++j) {
            float s = s_cs[j][tid];
            int   i = s_ci[j][tid];
            bool better = (s < fbs) || (s == fbs && i < fbi);
            if (better)                                { fss = fbs; fsi = fbi; fbs = s; fbi = i; }
            else if (s < fss || (s == fss && i < fsi)) { fss = s;   fsi = i; }
        }
        int fin = fbi;
        if (fss - fbs < 0.02f) {
            // fp64 re-evaluation of the two candidates: exact argmin decision
            const float* xq = x + (size_t)b * D * HW + hw0 + tid;
            const float* e0 = emb + fbi * D;
            const float* e1 = emb + fsi * D;
            double s0 = 0.0, s1 = 0.0;
            for (int d = 0; d < D; ++d) {
                double xv  = (double)xq[(size_t)d * HW];
                double ev0 = (double)e0[d];
                double ev1 = (double)e1[d];
                s0 += ev0 * (ev0 - 2.0 * xv);   // e^2 - 2 x e
                s1 += ev1 * (ev1 - 2.0 * xv);
            }
            if (s1 < s0 || (s1 == s0 && fsi < fbi)) fin = fsi;
        }
        s_idx[tid] = fin;
    }
    __syncthreads();

    // ---- one-hot write: 64 rows x 512 cols, coalesced float4, branchless ----
    {
        float4* encb = (float4*)(enc + (size_t)pixbase * K);
        #pragma unroll
        for (int it = 0; it < (PIX_PER_BLK * K / 4) / TPB; ++it) {  // 32 iters
            int e4  = it * TPB + tid;        // 0..8191
            int row = e4 >> 7;               // 128 float4 per row
            int kk  = (e4 & 127) << 2;
            int id  = s_idx[row];
            float4 v;
            v.x = (id == kk + 0) ? 1.0f : 0.0f;
            v.y = (id == kk + 1) ? 1.0f : 0.0f;
            v.z = (id == kk + 2) ? 1.0f : 0.0f;
            v.w = (id == kk + 3) ? 1.0f : 0.0f;
            encb[e4] = v;
        }
    }

    // ---- quantized write: quant[b][c][hw0+p] = emb[idx[p]][c], coalesced stores ----
    {
        const int p  = tid & 63;
        const int c0 = tid >> 6;             // 0..3 (wave)
        const int id = s_idx[p];
        float* qb = quant + (size_t)b * D * HW + hw0 + p;
        #pragma unroll
        for (int j = 0; j < 16; ++j) {
            int c = c0 * 16 + j;
            qb[(size_t)c * HW] = emb[id * D + c];
        }
    }
}

extern "C" void kernel_launch(void* const* d_in, const int* in_sizes, int n_in,
                              void* d_out, int out_size, void* d_ws, size_t ws_size,
                              hipStream_t stream)
{
    const float* x   = (const float*)d_in[0];
    const float* emb = (const float*)d_in[1];
    float* enc   = (float*)d_out;
    float* quant = (float*)d_out + (size_t)N * K;

    hipLaunchKernelGGL(vq_kernel, dim3(N / PIX_PER_BLK), dim3(TPB), 0, stream,
                       x, emb, enc, quant);
}

// Round 2
// 71.388 us; speedup vs baseline: 1.6373x; 1.6373x over previous
//
#include <hip/hip_runtime.h>

// VQ nearest-codebook: x [16,64,64,64] NCHW fp32, emb [512,64] fp32.
// out = concat(one_hot [65536,512] f32, quantized [16,64,64,64] f32).
//
// Strategy: scores = e_sq - 2*(X @ E^T) via bf16 hi/lo split MFMA (3 passes
// accumulated in fp32 => abs err ~1e-3), in-register top-2 per pixel,
// fp64 re-check of top-2 when gap < 0.125 (proven exact in rounds 0/1).

constexpr int D   = 64;
constexpr int K   = 512;
constexpr int N   = 65536;
constexpr int HW  = 4096;
constexpr int TPB = 256;
constexpr int PIX = 64;          // pixels per block
constexpr int CHUNK = 128;       // codes staged per chunk
constexpr int NCHUNK = K / CHUNK;            // 4
constexpr int TILES_PER_CHUNK = CHUNK / 16;  // 8

typedef __attribute__((ext_vector_type(8))) short bf16x8;
typedef __attribute__((ext_vector_type(4))) short short4v;
typedef __attribute__((ext_vector_type(4))) float f32x4;

__device__ inline unsigned short f2bf(float f) {           // RNE f32->bf16
    unsigned u = __builtin_bit_cast(unsigned, f);
    unsigned r = u + 0x7fffu + ((u >> 16) & 1u);
    return (unsigned short)(r >> 16);
}
__device__ inline float bf2f(unsigned short h) {
    unsigned u = ((unsigned)h) << 16;
    return __builtin_bit_cast(float, u);
}

// swizzled element offset into a [row][64] short tile: XOR elem bits 3..5
#define XOFF(row, d) (((row) << 6) + ((d) ^ (((row) & 7) << 3)))

__global__ __launch_bounds__(TPB, 3) void vq_mfma_kernel(
    const float* __restrict__ x, const float* __restrict__ emb,
    float* __restrict__ enc, float* __restrict__ quant)
{
    __shared__ short s_xh[PIX * D];      // 8 KB  (swizzled)
    __shared__ short s_xl[PIX * D];      // 8 KB
    __shared__ short s_eh[CHUNK * D];    // 16 KB (swizzled, per chunk)
    __shared__ short s_el[CHUNK * D];    // 16 KB
    __shared__ float s_esq[CHUNK];       // per-chunk ||e||^2
    __shared__ int   s_bidx[PIX];
    __shared__ int   s_sidx[PIX];
    __shared__ float s_gap[PIX];

    const int tid  = threadIdx.x;
    const int lane = tid & 63;
    const int wave = __builtin_amdgcn_readfirstlane(tid >> 6);
    const int g    = lane >> 4;        // 4-lane-group id (k-slice group)
    const int cl   = lane & 15;        // entity column within MFMA tile

    const int pixbase = blockIdx.x * PIX;
    const int b   = pixbase >> 12;
    const int hw0 = pixbase & (HW - 1);

    const float*  xb   = x + (size_t)b * D * HW + hw0;   // xb[d*HW + p]
    const float4* emb4 = (const float4*)emb;

    // ---------------- stage x tile: hi/lo bf16, swizzled [p][d] ----------------
    {
        const int p  = tid & 63;
        const int db = tid >> 6;                 // 0..3 -> d block of 16
        #pragma unroll
        for (int i = 0; i < 4; ++i) {
            const int d0 = db * 16 + i * 4;
            float v0 = xb[(size_t)(d0 + 0) * HW + p];
            float v1 = xb[(size_t)(d0 + 1) * HW + p];
            float v2 = xb[(size_t)(d0 + 2) * HW + p];
            float v3 = xb[(size_t)(d0 + 3) * HW + p];
            unsigned short h0 = f2bf(v0), h1 = f2bf(v1), h2 = f2bf(v2), h3 = f2bf(v3);
            short4v hv = { (short)h0, (short)h1, (short)h2, (short)h3 };
            short4v lv = { (short)f2bf(v0 - bf2f(h0)), (short)f2bf(v1 - bf2f(h1)),
                           (short)f2bf(v2 - bf2f(h2)), (short)f2bf(v3 - bf2f(h3)) };
            const int off = XOFF(p, d0);
            *(short4v*)&s_xh[off] = hv;
            *(short4v*)&s_xl[off] = lv;
        }
    }

    // ---------------- per-lane top-2 state (4 pixel rows each) ----------------
    float bs[4], ss[4];
    int   bi[4], si[4];
    #pragma unroll
    for (int r = 0; r < 4; ++r) { bs[r] = 3.4e38f; ss[r] = 3.4e38f; bi[r] = 0x7fffffff; si[r] = 0x7fffffff; }

    bf16x8 ah0, ah1, al0, al1;   // A fragments (loaded after first sync)

    for (int chunk = 0; chunk < NCHUNK; ++chunk) {
        if (chunk > 0) __syncthreads();   // prev compute done before restage

        // -------- stage codebook chunk: hi/lo bf16 swizzled + e_sq --------
        #pragma unroll
        for (int i = 0; i < 8; ++i) {
            const int f4idx = i * 256 + tid;
            float4 f = emb4[chunk * (CHUNK * 16) + f4idx];
            const int code = f4idx >> 4;            // 0..127 chunk-local
            const int d0   = (f4idx & 15) << 2;
            unsigned short h0 = f2bf(f.x), h1 = f2bf(f.y), h2 = f2bf(f.z), h3 = f2bf(f.w);
            short4v hv = { (short)h0, (short)h1, (short)h2, (short)h3 };
            short4v lv = { (short)f2bf(f.x - bf2f(h0)), (short)f2bf(f.y - bf2f(h1)),
                           (short)f2bf(f.z - bf2f(h2)), (short)f2bf(f.w - bf2f(h3)) };
            const int off = XOFF(code, d0);
            *(short4v*)&s_eh[off] = hv;
            *(short4v*)&s_el[off] = lv;
            float pe = f.x * f.x + f.y * f.y + f.z * f.z + f.w * f.w;
            pe += __shfl_xor(pe, 1);
            pe += __shfl_xor(pe, 2);
            pe += __shfl_xor(pe, 4);
            pe += __shfl_xor(pe, 8);
            if ((tid & 15) == 0) s_esq[code] = pe;
        }
        __syncthreads();

        if (chunk == 0) {   // x ready now: load wave's A fragments once
            const int xrow = wave * 16 + cl;
            ah0 = *(const bf16x8*)&s_xh[XOFF(xrow, g * 8)];
            ah1 = *(const bf16x8*)&s_xh[XOFF(xrow, 32 + g * 8)];
            al0 = *(const bf16x8*)&s_xl[XOFF(xrow, g * 8)];
            al1 = *(const bf16x8*)&s_xl[XOFF(xrow, 32 + g * 8)];
        }

        // -------- 8 code tiles: 6 MFMA each (hh k0/k1, hl k0/k1, lh k0/k1) --------
        #pragma unroll
        for (int ct = 0; ct < TILES_PER_CHUNK; ++ct) {
            const int code = ct * 16 + cl;
            bf16x8 bh0 = *(const bf16x8*)&s_eh[XOFF(code, g * 8)];
            bf16x8 bh1 = *(const bf16x8*)&s_eh[XOFF(code, 32 + g * 8)];
            bf16x8 bl0 = *(const bf16x8*)&s_el[XOFF(code, g * 8)];
            bf16x8 bl1 = *(const bf16x8*)&s_el[XOFF(code, 32 + g * 8)];
            f32x4 c = {0.f, 0.f, 0.f, 0.f};
            c = __builtin_amdgcn_mfma_f32_16x16x32_bf16(ah0, bh0, c, 0, 0, 0);
            c = __builtin_amdgcn_mfma_f32_16x16x32_bf16(ah1, bh1, c, 0, 0, 0);
            c = __builtin_amdgcn_mfma_f32_16x16x32_bf16(ah0, bl0, c, 0, 0, 0);
            c = __builtin_amdgcn_mfma_f32_16x16x32_bf16(ah1, bl1, c, 0, 0, 0);
            c = __builtin_amdgcn_mfma_f32_16x16x32_bf16(al0, bh0, c, 0, 0, 0);
            c = __builtin_amdgcn_mfma_f32_16x16x32_bf16(al1, bh1, c, 0, 0, 0);
            const float eq    = s_esq[code];
            const int   kcode = chunk * CHUNK + code;
            #pragma unroll
            for (int r = 0; r < 4; ++r) {
                float s = fmaf(-2.0f, c[r], eq);   // x_sq dropped (row-constant)
                bool c1 = s < bs[r];
                bool c2 = s < ss[r];
                ss[r] = c1 ? bs[r] : (c2 ? s : ss[r]);
                si[r] = c1 ? bi[r] : (c2 ? kcode : si[r]);
                bs[r] = c1 ? s : bs[r];
                bi[r] = c1 ? kcode : bi[r];
            }
        }
    }

    // ---------------- cross-lane top-2 merge (16 lanes share a row-group) ----------------
    #pragma unroll
    for (int r = 0; r < 4; ++r) {
        for (int m = 1; m <= 8; m <<= 1) {
            float obs = __shfl_xor(bs[r], m); int obi = __shfl_xor(bi[r], m);
            float oss = __shfl_xor(ss[r], m); int osi = __shfl_xor(si[r], m);
            {   // insert (obs,obi) with index tie-break
                bool c1 = (obs < bs[r]) || (obs == bs[r] && obi < bi[r]);
                bool c2 = (obs < ss[r]) || (obs == ss[r] && obi < si[r]);
                ss[r] = c1 ? bs[r] : (c2 ? obs : ss[r]);
                si[r] = c1 ? bi[r] : (c2 ? obi : si[r]);
                bs[r] = c1 ? obs : bs[r];
                bi[r] = c1 ? obi : bi[r];
            }
            {   // insert (oss,osi)
                bool c1 = (oss < bs[r]) || (oss == bs[r] && osi < bi[r]);
                bool c2 = (oss < ss[r]) || (oss == ss[r] && osi < si[r]);
                ss[r] = c1 ? bs[r] : (c2 ? oss : ss[r]);
                si[r] = c1 ? bi[r] : (c2 ? osi : si[r]);
                bs[r] = c1 ? oss : bs[r];
                bi[r] = c1 ? osi : bi[r];
            }
        }
    }
    if (cl == 0) {
        #pragma unroll
        for (int r = 0; r < 4; ++r) {
            const int pix = wave * 16 + g * 4 + r;   // C/D layout: row=(lane>>4)*4+reg
            s_bidx[pix] = bi[r];
            s_sidx[pix] = si[r];
            s_gap[pix]  = ss[r] - bs[r];
        }
    }
    __syncthreads();

    // ---------------- fp64 refinement of near-ties (exact argmin) ----------------
    if (tid < PIX) {
        if (s_gap[tid] < 0.125f) {
            const int i0 = s_bidx[tid], i1 = s_sidx[tid];
            const float* xq = xb + tid;
            const float* e0 = emb + (size_t)i0 * D;
            const float* e1 = emb + (size_t)i1 * D;
            double s0 = 0.0, s1 = 0.0;
            for (int d = 0; d < D; ++d) {
                double xv  = (double)xq[(size_t)d * HW];
                double ev0 = (double)e0[d];
                double ev1 = (double)e1[d];
                s0 += ev0 * (ev0 - 2.0 * xv);
                s1 += ev1 * (ev1 - 2.0 * xv);
            }
            if (s1 < s0 || (s1 == s0 && i1 < i0)) s_bidx[tid] = i1;
        }
    }
    __syncthreads();

    // ---------------- one-hot write: 64 rows x 512, coalesced float4 ----------------
    {
        float4* encb = (float4*)(enc + (size_t)pixbase * K);
        #pragma unroll
        for (int it = 0; it < (PIX * K / 4) / TPB; ++it) {   // 32 iters
            int e4  = it * TPB + tid;
            int row = e4 >> 7;
            int kk  = (e4 & 127) << 2;
            int id  = s_bidx[row];
            float4 v;
            v.x = (id == kk + 0) ? 1.0f : 0.0f;
            v.y = (id == kk + 1) ? 1.0f : 0.0f;
            v.z = (id == kk + 2) ? 1.0f : 0.0f;
            v.w = (id == kk + 3) ? 1.0f : 0.0f;
            encb[e4] = v;
        }
    }

    // ---------------- quantized write: coalesced per-channel stores ----------------
    {
        const int p  = tid & 63;
        const int c0 = tid >> 6;
        const int id = s_bidx[p];
        float* qb = quant + (size_t)b * D * HW + hw0 + p;
        #pragma unroll
        for (int j = 0; j < 16; ++j) {
            int ch = c0 * 16 + j;
            qb[(size_t)ch * HW] = emb[(size_t)id * D + ch];
        }
    }
}

extern "C" void kernel_launch(void* const* d_in, const int* in_sizes, int n_in,
                              void* d_out, int out_size, void* d_ws, size_t ws_size,
                              hipStream_t stream)
{
    const float* x   = (const float*)d_in[0];
    const float* emb = (const float*)d_in[1];
    float* enc   = (float*)d_out;
    float* quant = (float*)d_out + (size_t)N * K;

    hipLaunchKernelGGL(vq_mfma_kernel, dim3(N / PIX), dim3(TPB), 0, stream,
                       x, emb, enc, quant);
}